// Round 5
// baseline (303.553 us; speedup 1.0000x reference)
//
#include <hip/hip_runtime.h>
#include <hip/hip_bf16.h>

// Problem constants (match reference)
#define C_CLS 10
#define DIM   3072
#define HID   512
#define LAT   256
#define BATCH 2048
#define BM    64          // GEMM M-tile
#define GRID_TILES 42     // max sum ceil(cnt_c/64) = 32 + 10

typedef __attribute__((ext_vector_type(8))) short  s16x8;
typedef __attribute__((ext_vector_type(4))) float  f32x4;
typedef __attribute__((ext_vector_type(8))) __bf16 bf16x8;

struct Meta {
    int offsets[C_CLS + 1];
    int ntiles;
    int tileClass[GRID_TILES];
    int tileRow[GRID_TILES];
    int perm[BATCH];        // perm[p] = original row index
};

__device__ __forceinline__ unsigned short f2bf(float f) {
    unsigned u = __builtin_bit_cast(unsigned, f);
    unsigned r = (u + 0x7fffu + ((u >> 16) & 1u)) >> 16;   // RNE
    return (unsigned short)r;
}

__device__ __forceinline__ f32x4 mfma16(s16x8 a, s16x8 b, f32x4 c) {
    return __builtin_amdgcn_mfma_f32_16x16x32_bf16(
        __builtin_bit_cast(bf16x8, a), __builtin_bit_cast(bf16x8, b), c, 0, 0, 0);
}

// ---------------- setup: histogram -> offsets -> tile map -> perm ----------------
__global__ __launch_bounds__(256) void setup_kernel(const int* __restrict__ label,
                                                    Meta* __restrict__ mt,
                                                    float* __restrict__ out) {
    __shared__ int h[C_CLS];
    __shared__ int loff[C_CLS + 1];
    int tid = threadIdx.x;
    if (tid < C_CLS) h[tid] = 0;
    __syncthreads();
    for (int i = tid; i < BATCH; i += 256) atomicAdd(&h[label[i]], 1);
    __syncthreads();
    if (tid == 0) {
        int s = 0, nt = 0;
        for (int c = 0; c < C_CLS; ++c) { loff[c] = s; s += h[c]; }
        loff[C_CLS] = s;
        for (int c = 0; c < C_CLS; ++c) {
            mt->offsets[c] = loff[c];
            int cnt = h[c];
            for (int t = 0; t < cnt; t += BM) {
                mt->tileClass[nt] = c;
                mt->tileRow[nt]   = loff[c] + t;
                ++nt;
            }
            h[c] = loff[c];              // reuse as cursor
        }
        mt->offsets[C_CLS] = loff[C_CLS];
        mt->ntiles = nt;
        out[0] = 0.0f;                   // loss accumulator (d_out poisoned each call)
    }
    __syncthreads();
    for (int i = tid; i < BATCH; i += 256) {
        int pos = atomicAdd(&h[label[i]], 1);
        mt->perm[pos] = i;
    }
}

// ---------------- fused split-K GEMM ----------------
// A: NPART==0 -> gather f32 img rows via perm (layer 1)
//    NPART>0  -> sum of NPART f32 partial buffers [NPART][BATCH][KTOT]
//                + abias[c][k] (+ReLU if RELUIN), converted to bf16 in-register
// B: f32 weights [C][KTOT][N], transposed+converted during LDS staging
// Out: !FINAL -> pre-bias f32 partial [KSPLIT][BATCH][N] at z=blockIdx.z
//      FINAL  -> bias + scatter via perm + MSE loss atomic
// 64x64 tile, BK=64, 2x2 waves of 32x32, double-buffered LDS, 2-phase pipeline.
// LDS swizzle: 16B k-slot s of row r stored at slot s ^ (r & 7)
template <int KTOT, int KSPLIT, int N, int NPART, bool RELUIN, bool FINAL>
__global__ __launch_bounds__(256) void gemm_kernel(const float* __restrict__ Ain,
                                                   const float* __restrict__ abias,
                                                   const float* __restrict__ W,
                                                   const float* __restrict__ obias,
                                                   float* __restrict__ Pout,
                                                   float* __restrict__ outF,
                                                   const float* __restrict__ img,
                                                   const Meta* __restrict__ mt) {
    int ty = blockIdx.y;
    if (ty >= mt->ntiles) return;
    const int c     = mt->tileClass[ty];
    const int r0    = mt->tileRow[ty];
    const int rend  = mt->offsets[c + 1];
    const int n0    = blockIdx.x * 64;
    const int kbase = blockIdx.z * (KTOT / KSPLIT);
    constexpr int NT = KTOT / KSPLIT / 64;

    const float* Wc = W + (size_t)c * KTOT * N + n0;   // (k, nl) at Wc[k*N + nl]

    __shared__ __align__(16) unsigned short As[2][64 * 64];
    __shared__ __align__(16) unsigned short Bs[2][64 * 64];

    const int tid  = threadIdx.x;
    const int lane = tid & 63;
    const int wid  = tid >> 6;
    const int wm   = wid >> 1, wn = wid & 1;   // 2x2 wave grid, 32x32 each

    // staging roles
    const int aRow0 = tid >> 3;                // A chunk-0 row (chunk 1 row = +32)
    const int aSlot = tid & 7;                 // 16B k-slot within row
    const int bO    = tid >> 5;                // B k-octet 0..7
    const int bN2   = tid & 31;                // B n-pair 0..31

    constexpr int NP = (NPART == 0) ? 1 : NPART;
    float4 ga[NP][2][2];       // A loads: [partial][h-chunk][lo/hi float4]
    float4 gbias[2];           // abias slice (k-dependent only)
    float2 bb[8];              // B: 8 k-rows x 2 n

    auto load_tile = [&](int k0) {
#pragma unroll
        for (int h = 0; h < 2; ++h) {
            int row = aRow0 + h * 32;
            int ar  = min(r0 + row, rend - 1);           // clamp partial tile
            if constexpr (NPART == 0) {
                int orig = mt->perm[ar];
                const float* src = Ain + (size_t)orig * KTOT + k0 + aSlot * 8;
                ga[0][h][0] = *(const float4*)(src);
                ga[0][h][1] = *(const float4*)(src + 4);
            } else {
#pragma unroll
                for (int p = 0; p < NP; ++p) {
                    const float* src = Ain + ((size_t)p * BATCH + ar) * KTOT + k0 + aSlot * 8;
                    ga[p][h][0] = *(const float4*)(src);
                    ga[p][h][1] = *(const float4*)(src + 4);
                }
            }
        }
        if constexpr (NPART > 0) {
            const float* bsrc = abias + (size_t)c * KTOT + k0 + aSlot * 8;
            gbias[0] = *(const float4*)(bsrc);
            gbias[1] = *(const float4*)(bsrc + 4);
        }
        const float* src = Wc + (size_t)(k0 + 8 * bO) * N + 2 * bN2;
#pragma unroll
        for (int i = 0; i < 8; ++i) bb[i] = *(const float2*)(src + (size_t)i * N);
    };

    auto write_tile = [&](int buf) {
#pragma unroll
        for (int h = 0; h < 2; ++h) {
            int row = aRow0 + h * 32;
            s16x8 v;
#pragma unroll
            for (int q = 0; q < 2; ++q)
#pragma unroll
                for (int j = 0; j < 4; ++j) {
                    float s;
                    if constexpr (NPART == 0) {
                        s = ((const float*)&ga[0][h][q])[j];
                    } else {
                        s = ((const float*)&gbias[q])[j];
#pragma unroll
                        for (int p = 0; p < NP; ++p) s += ((const float*)&ga[p][h][q])[j];
                        if (RELUIN) s = fmaxf(s, 0.0f);
                    }
                    ((unsigned short*)&v)[q * 4 + j] = f2bf(s);
                }
            *(s16x8*)(&As[buf][row * 64 + ((aSlot ^ (row & 7))) * 8]) = v;
        }
#pragma unroll
        for (int nn = 0; nn < 2; ++nn) {
            int n = 2 * bN2 + nn;
            s16x8 v;
#pragma unroll
            for (int i = 0; i < 8; ++i)
                ((unsigned short*)&v)[i] = f2bf(nn ? bb[i].y : bb[i].x);
            *(s16x8*)(&Bs[buf][n * 64 + ((bO ^ (n & 7))) * 8]) = v;
        }
    };

    f32x4 acc[2][2] = {};

    load_tile(kbase);
    write_tile(0);
    __syncthreads();

    for (int t = 0; t < NT; ++t) {
        int cur = t & 1;
        if (t + 1 < NT) load_tile(kbase + (t + 1) * 64);   // issue next loads before compute
#pragma unroll
        for (int ks = 0; ks < 2; ++ks) {
            int kslot = ks * 4 + (lane >> 4);
            int rA0 = wm * 32 + (lane & 15), rA1 = rA0 + 16;
            int rB0 = wn * 32 + (lane & 15), rB1 = rB0 + 16;
            s16x8 a0 = *(const s16x8*)(&As[cur][rA0 * 64 + (kslot ^ (rA0 & 7)) * 8]);
            s16x8 a1 = *(const s16x8*)(&As[cur][rA1 * 64 + (kslot ^ (rA1 & 7)) * 8]);
            s16x8 b0 = *(const s16x8*)(&Bs[cur][rB0 * 64 + (kslot ^ (rB0 & 7)) * 8]);
            s16x8 b1 = *(const s16x8*)(&Bs[cur][rB1 * 64 + (kslot ^ (rB1 & 7)) * 8]);
            acc[0][0] = mfma16(a0, b0, acc[0][0]);
            acc[0][1] = mfma16(a0, b1, acc[0][1]);
            acc[1][0] = mfma16(a1, b0, acc[1][0]);
            acc[1][1] = mfma16(a1, b1, acc[1][1]);
        }
        if (t + 1 < NT) write_tile(cur ^ 1);
        __syncthreads();
    }

    // ---- epilogue.  C/D layout: col = lane&15, row = (lane>>4)*4 + reg ----
    const int col = lane & 15;
    const int rq  = lane >> 4;
    if constexpr (!FINAL) {
        float* P = Pout + (size_t)blockIdx.z * BATCH * N;
#pragma unroll
        for (int mi = 0; mi < 2; ++mi)
#pragma unroll
            for (int ni = 0; ni < 2; ++ni) {
                int n = n0 + wn * 32 + ni * 16 + col;
#pragma unroll
                for (int r = 0; r < 4; ++r) {
                    int m = r0 + wm * 32 + mi * 16 + rq * 4 + r;
                    if (m < rend) P[(size_t)m * N + n] = acc[mi][ni][r];
                }
            }
    } else {
        float lsum = 0.0f;
#pragma unroll
        for (int mi = 0; mi < 2; ++mi) {
#pragma unroll
            for (int r = 0; r < 4; ++r) {
                int m = r0 + wm * 32 + mi * 16 + rq * 4 + r;
                if (m < rend) {
                    int orig = mt->perm[m];
#pragma unroll
                    for (int ni = 0; ni < 2; ++ni) {
                        int n   = n0 + wn * 32 + ni * 16 + col;
                        float v = acc[mi][ni][r] + obias[(size_t)c * N + n];
                        size_t idx = (size_t)orig * N + n;
                        outF[1 + idx] = v;
                        float d = v - img[idx];
                        lsum += d * d;
                    }
                }
            }
        }
#pragma unroll
        for (int o = 32; o > 0; o >>= 1) lsum += __shfl_down(lsum, o);
        __shared__ float red[4];
        if (lane == 0) red[wid] = lsum;
        __syncthreads();
        if (tid == 0)
            atomicAdd(&outF[0],
                      (red[0] + red[1] + red[2] + red[3]) * (1.0f / ((float)BATCH * (float)DIM)));
    }
}

// ---------------- launch ----------------
extern "C" void kernel_launch(void* const* d_in, const int* in_sizes, int n_in,
                              void* d_out, int out_size, void* d_ws, size_t ws_size,
                              hipStream_t stream) {
    const float* img    = (const float*)d_in[0];
    const int*   label  = (const int*)d_in[1];
    const float* enc_w1 = (const float*)d_in[2];
    const float* enc_b1 = (const float*)d_in[3];
    const float* enc_w2 = (const float*)d_in[4];
    const float* enc_b2 = (const float*)d_in[5];
    const float* dec_w1 = (const float*)d_in[6];
    const float* dec_b1 = (const float*)d_in[7];
    const float* dec_w2 = (const float*)d_in[8];
    const float* dec_b2 = (const float*)d_in[9];
    float* out = (float*)d_out;

    auto alignup = [](size_t x) { return (x + 255) & ~(size_t)255; };
    char* p = (char*)d_ws;
    size_t off = 0;
    Meta* meta = (Meta*)p;                  off += alignup(sizeof(Meta));
    float* P1  = (float*)(p + off);         off += alignup((size_t)4 * BATCH * HID * 4);   // L1 partials
    float* PZ  = (float*)(p + off);         off += alignup((size_t)4 * BATCH * LAT * 4);   // L2 partials
    float* PH2 = (float*)(p + off);         off += alignup((size_t)2 * BATCH * HID * 4);   // L3 partials
    (void)ws_size; (void)in_sizes; (void)n_in; (void)out_size;

    setup_kernel<<<1, 256, 0, stream>>>(label, meta, out);

    // L1: img @ enc_w1 -> P1 (pre-bias), split-K=4 (K=3072 -> 768/block, 1344 blocks)
    gemm_kernel<DIM, 4, HID, 0, false, false><<<dim3(HID / 64, GRID_TILES, 4), 256, 0, stream>>>(
        img, nullptr, enc_w1, nullptr, P1, nullptr, nullptr, meta);
    // L2: relu(P1+b1) @ enc_w2 -> PZ, split-K=4 (K=512 -> 128/block, 672 blocks)
    gemm_kernel<HID, 4, LAT, 4, true, false><<<dim3(LAT / 64, GRID_TILES, 4), 256, 0, stream>>>(
        P1, enc_b1, enc_w2, nullptr, PZ, nullptr, nullptr, meta);
    // L3: (PZ+b2) @ dec_w1 -> PH2, split-K=2 (K=256 -> 128/block, 672 blocks)
    gemm_kernel<LAT, 2, HID, 4, false, false><<<dim3(HID / 64, GRID_TILES, 2), 256, 0, stream>>>(
        PZ, enc_b2, dec_w1, nullptr, PH2, nullptr, nullptr, meta);
    // L4: relu(PH2+b3) @ dec_w2 + b4 -> scatter + loss (2016 blocks, no split)
    gemm_kernel<HID, 1, DIM, 2, true, true><<<dim3(DIM / 64, GRID_TILES, 1), 256, 0, stream>>>(
        PH2, dec_b1, dec_w2, dec_b2, nullptr, out, img, meta);
}

// Round 10
// 277.520 us; speedup vs baseline: 1.0938x; 1.0938x over previous
//
#include <hip/hip_runtime.h>
#include <hip/hip_bf16.h>

// Problem constants (match reference)
#define C_CLS 10
#define DIM   3072
#define HID   512
#define LAT   256
#define BATCH 2048
#define BM    64          // GEMM M-tile
#define GRID_TILES 42     // max sum ceil(cnt_c/64) = 32 + 10

typedef __attribute__((ext_vector_type(8))) short  s16x8;
typedef __attribute__((ext_vector_type(4))) float  f32x4;
typedef __attribute__((ext_vector_type(8))) __bf16 bf16x8;

struct Meta {
    int offsets[C_CLS + 1];
    int ntiles;
    int tileClass[GRID_TILES];
    int tileRow[GRID_TILES];
    int perm[BATCH];        // perm[p] = original row index
    int rowcls[BATCH];      // rowcls[p] = class of permuted row p
};

__device__ __forceinline__ unsigned short f2bf(float f) {
    unsigned u = __builtin_bit_cast(unsigned, f);
    unsigned r = (u + 0x7fffu + ((u >> 16) & 1u)) >> 16;   // RNE
    return (unsigned short)r;
}

__device__ __forceinline__ f32x4 mfma16(s16x8 a, s16x8 b, f32x4 c) {
    return __builtin_amdgcn_mfma_f32_16x16x32_bf16(
        __builtin_bit_cast(bf16x8, a), __builtin_bit_cast(bf16x8, b), c, 0, 0, 0);
}

// ---------------- setup: histogram -> offsets -> tile map -> perm ----------------
__global__ __launch_bounds__(256) void setup_kernel(const int* __restrict__ label,
                                                    Meta* __restrict__ mt,
                                                    float* __restrict__ out) {
    __shared__ int h[C_CLS];
    __shared__ int loff[C_CLS + 1];
    int tid = threadIdx.x;
    if (tid < C_CLS) h[tid] = 0;
    __syncthreads();
    for (int i = tid; i < BATCH; i += 256) atomicAdd(&h[label[i]], 1);
    __syncthreads();
    if (tid == 0) {
        int s = 0, nt = 0;
        for (int c = 0; c < C_CLS; ++c) { loff[c] = s; s += h[c]; }
        loff[C_CLS] = s;
        for (int c = 0; c < C_CLS; ++c) {
            mt->offsets[c] = loff[c];
            int cnt = h[c];
            for (int t = 0; t < cnt; t += BM) {
                mt->tileClass[nt] = c;
                mt->tileRow[nt]   = loff[c] + t;
                ++nt;
            }
            h[c] = loff[c];              // reuse as cursor
        }
        mt->offsets[C_CLS] = loff[C_CLS];
        mt->ntiles = nt;
        out[0] = 0.0f;                   // loss accumulator (d_out poisoned each call)
    }
    __syncthreads();
    for (int i = tid; i < BATCH; i += 256) {
        int lb  = label[i];
        int pos = atomicAdd(&h[lb], 1);
        mt->perm[pos]   = i;
        mt->rowcls[pos] = lb;
    }
}

// ---------------- gather img rows into label-sorted order, f32 -> bf16 ----------------
__global__ __launch_bounds__(256) void gather_kernel(const float* __restrict__ img,
                                                     const Meta* __restrict__ mt,
                                                     unsigned short* __restrict__ Xg) {
    int p    = blockIdx.x;
    int orig = mt->perm[p];
    const float4* src = (const float4*)(img + (size_t)orig * DIM);
    unsigned short* dst = Xg + (size_t)p * DIM;
    for (int j = threadIdx.x; j < DIM / 4; j += 256) {
        float4 v = src[j];
        unsigned short o[4] = {f2bf(v.x), f2bf(v.y), f2bf(v.z), f2bf(v.w)};
        *(uint2*)(dst + 4 * j) = *(const uint2*)o;
    }
}

// ---------------- reduce: sum KS partials + bias (+ReLU) -> bf16 activation ----------------
// P: [KS][BATCH][N] f32 (pre-bias),  out: [BATCH][N] bf16 (permuted row order)
template <int N, int KS, bool RELU>
__global__ __launch_bounds__(256) void reduce_kernel(const float* __restrict__ P,
                                                     const float* __restrict__ bias,
                                                     const Meta* __restrict__ mt,
                                                     unsigned short* __restrict__ out) {
    int idx = blockIdx.x * 256 + threadIdx.x;    // one thread = 8 elements
    int p   = idx / (N / 8);
    int n8  = idx - p * (N / 8);
    const float* b = bias + (size_t)mt->rowcls[p] * N + n8 * 8;
    f32x4 s0 = *(const f32x4*)(b);
    f32x4 s1 = *(const f32x4*)(b + 4);
#pragma unroll
    for (int ks = 0; ks < KS; ++ks) {
        const float* src = P + ((size_t)ks * BATCH + p) * N + n8 * 8;
        s0 += *(const f32x4*)(src);
        s1 += *(const f32x4*)(src + 4);
    }
    s16x8 v;
#pragma unroll
    for (int j = 0; j < 4; ++j) {
        float a = s0[j], c = s1[j];
        if (RELU) { a = fmaxf(a, 0.0f); c = fmaxf(c, 0.0f); }
        ((unsigned short*)&v)[j]     = f2bf(a);
        ((unsigned short*)&v)[4 + j] = f2bf(c);
    }
    *(s16x8*)(out + (size_t)p * N + n8 * 8) = v;
}

// ---------------- fused split-K GEMM ----------------
// A: bf16 [BATCH][KTOT], permuted row order
// B: f32 weights [C][KTOT][N], transposed+converted during LDS staging
// Out: !FINAL -> pre-bias f32 partial [KSPLIT][BATCH][N] at z=blockIdx.z
//      FINAL  -> bias + scatter via perm + MSE loss atomic
// 64x64 tile, BK=64, 2x2 waves of 32x32.
// 3-stage pipeline: 2 register stages + LDS ping-pong, 1 barrier per K-step.
// LDS swizzle: 16B k-slot s of row r stored at slot s ^ (r & 7)
template <int KTOT, int KSPLIT, int N, bool FINAL>
__global__ __launch_bounds__(256) void gemm_kernel(const unsigned short* __restrict__ Ain,
                                                   const float* __restrict__ W,
                                                   const float* __restrict__ obias,
                                                   float* __restrict__ Pout,
                                                   float* __restrict__ outF,
                                                   const float* __restrict__ img,
                                                   const Meta* __restrict__ mt) {
    constexpr int NT = KTOT / KSPLIT / 64;
    static_assert(NT >= 2 && (NT % 2) == 0, "NT must be even and >= 2");

    int ty = blockIdx.y;
    if (ty >= mt->ntiles) return;
    const int c     = mt->tileClass[ty];
    const int r0    = mt->tileRow[ty];
    const int rend  = mt->offsets[c + 1];
    const int n0    = blockIdx.x * 64;
    const int kbase = blockIdx.z * (KTOT / KSPLIT);

    const float* Wc = W + (size_t)c * KTOT * N + n0;   // (k, nl) at Wc[k*N + nl]

    __shared__ __align__(16) unsigned short As[2][64 * 64];
    __shared__ __align__(16) unsigned short Bs[2][64 * 64];

    const int tid  = threadIdx.x;
    const int lane = tid & 63;
    const int wid  = tid >> 6;
    const int wm   = wid >> 1, wn = wid & 1;   // 2x2 wave grid, 32x32 each

    // staging roles
    const int aRow0 = tid >> 3;                // A chunk-0 row (chunk 1 row = +32)
    const int aSlot = tid & 7;                 // 16B k-slot within row
    const int bO    = tid >> 5;                // B k-octet 0..7
    const int bN2   = tid & 31;                // B n-pair 0..31

    struct Stage { s16x8 a0, a1; float2 b[8]; };
    Stage s0, s1;

    const int ar0 = min(r0 + aRow0, rend - 1);
    const int ar1 = min(r0 + aRow0 + 32, rend - 1);

    auto load_stage = [&](Stage& S, int k0) {
        S.a0 = *(const s16x8*)(Ain + (size_t)ar0 * KTOT + k0 + aSlot * 8);
        S.a1 = *(const s16x8*)(Ain + (size_t)ar1 * KTOT + k0 + aSlot * 8);
        const float* src = Wc + (size_t)(k0 + 8 * bO) * N + 2 * bN2;
#pragma unroll
        for (int i = 0; i < 8; ++i) S.b[i] = *(const float2*)(src + (size_t)i * N);
    };

    auto write_stage = [&](const Stage& S, int buf) {
        {
            int row = aRow0;
            *(s16x8*)(&As[buf][row * 64 + ((aSlot ^ (row & 7))) * 8]) = S.a0;
            row = aRow0 + 32;
            *(s16x8*)(&As[buf][row * 64 + ((aSlot ^ (row & 7))) * 8]) = S.a1;
        }
#pragma unroll
        for (int nn = 0; nn < 2; ++nn) {
            int n = 2 * bN2 + nn;
            s16x8 v;
#pragma unroll
            for (int i = 0; i < 8; ++i)
                ((unsigned short*)&v)[i] = f2bf(nn ? S.b[i].y : S.b[i].x);
            *(s16x8*)(&Bs[buf][n * 64 + ((bO ^ (n & 7))) * 8]) = v;
        }
    };

    f32x4 acc[2][2] = {};

    auto compute = [&](int buf) {
#pragma unroll
        for (int ks = 0; ks < 2; ++ks) {
            int kslot = ks * 4 + (lane >> 4);
            int rA0 = wm * 32 + (lane & 15), rA1 = rA0 + 16;
            int rB0 = wn * 32 + (lane & 15), rB1 = rB0 + 16;
            s16x8 a0 = *(const s16x8*)(&As[buf][rA0 * 64 + (kslot ^ (rA0 & 7)) * 8]);
            s16x8 a1 = *(const s16x8*)(&As[buf][rA1 * 64 + (kslot ^ (rA1 & 7)) * 8]);
            s16x8 b0 = *(const s16x8*)(&Bs[buf][rB0 * 64 + (kslot ^ (rB0 & 7)) * 8]);
            s16x8 b1 = *(const s16x8*)(&Bs[buf][rB1 * 64 + (kslot ^ (rB1 & 7)) * 8]);
            acc[0][0] = mfma16(a0, b0, acc[0][0]);
            acc[0][1] = mfma16(a0, b1, acc[0][1]);
            acc[1][0] = mfma16(a1, b0, acc[1][0]);
            acc[1][1] = mfma16(a1, b1, acc[1][1]);
        }
    };

    // prologue: stage tiles 0 and 1; tile 0 -> LDS buf0
    load_stage(s0, kbase);
    load_stage(s1, kbase + 64);
    write_stage(s0, 0);
    __syncthreads();

    for (int t = 0; t < NT; t += 2) {
        if (t + 2 < NT) load_stage(s0, kbase + (t + 2) * 64);   // issue early
        compute(0);                                             // tile t
        if (t + 1 < NT) write_stage(s1, 1);                     // tile t+1 -> buf1 (write late)
        __syncthreads();
        if (t + 3 < NT) load_stage(s1, kbase + (t + 3) * 64);
        compute(1);                                             // tile t+1
        if (t + 2 < NT) write_stage(s0, 0);                     // tile t+2 -> buf0
        __syncthreads();
    }

    // ---- epilogue.  C/D layout: col = lane&15, row = (lane>>4)*4 + reg ----
    const int col = lane & 15;
    const int rq  = lane >> 4;
    if constexpr (!FINAL) {
        float* P = Pout + (size_t)blockIdx.z * BATCH * N;
#pragma unroll
        for (int mi = 0; mi < 2; ++mi)
#pragma unroll
            for (int ni = 0; ni < 2; ++ni) {
                int n = n0 + wn * 32 + ni * 16 + col;
#pragma unroll
                for (int r = 0; r < 4; ++r) {
                    int m = r0 + wm * 32 + mi * 16 + rq * 4 + r;
                    if (m < rend) P[(size_t)m * N + n] = acc[mi][ni][r];
                }
            }
    } else {
        float lsum = 0.0f;
#pragma unroll
        for (int mi = 0; mi < 2; ++mi) {
#pragma unroll
            for (int r = 0; r < 4; ++r) {
                int m = r0 + wm * 32 + mi * 16 + rq * 4 + r;
                if (m < rend) {
                    int orig = mt->perm[m];
#pragma unroll
                    for (int ni = 0; ni < 2; ++ni) {
                        int n   = n0 + wn * 32 + ni * 16 + col;
                        float v = acc[mi][ni][r] + obias[(size_t)c * N + n];
                        size_t idx = (size_t)orig * N + n;
                        outF[1 + idx] = v;
                        float d = v - img[idx];
                        lsum += d * d;
                    }
                }
            }
        }
#pragma unroll
        for (int o = 32; o > 0; o >>= 1) lsum += __shfl_down(lsum, o);
        __shared__ float red[4];
        if (lane == 0) red[wid] = lsum;
        __syncthreads();
        if (tid == 0)
            atomicAdd(&outF[0],
                      (red[0] + red[1] + red[2] + red[3]) * (1.0f / ((float)BATCH * (float)DIM)));
    }
}

// ---------------- launch ----------------
extern "C" void kernel_launch(void* const* d_in, const int* in_sizes, int n_in,
                              void* d_out, int out_size, void* d_ws, size_t ws_size,
                              hipStream_t stream) {
    const float* img    = (const float*)d_in[0];
    const int*   label  = (const int*)d_in[1];
    const float* enc_w1 = (const float*)d_in[2];
    const float* enc_b1 = (const float*)d_in[3];
    const float* enc_w2 = (const float*)d_in[4];
    const float* enc_b2 = (const float*)d_in[5];
    const float* dec_w1 = (const float*)d_in[6];
    const float* dec_b1 = (const float*)d_in[7];
    const float* dec_w2 = (const float*)d_in[8];
    const float* dec_b2 = (const float*)d_in[9];
    float* out = (float*)d_out;

    auto alignup = [](size_t x) { return (x + 255) & ~(size_t)255; };
    char* p = (char*)d_ws;
    size_t off = 0;
    Meta* meta = (Meta*)p;                           off += alignup(sizeof(Meta));
    float* P1  = (float*)(p + off);                  off += alignup((size_t)4 * BATCH * HID * 4);
    float* P2  = (float*)(p + off);                  off += alignup((size_t)4 * BATCH * LAT * 4);
    float* P3  = (float*)(p + off);                  off += alignup((size_t)2 * BATCH * HID * 4);
    unsigned short* Xg = (unsigned short*)(p + off); off += alignup((size_t)BATCH * DIM * 2);
    unsigned short* H1 = (unsigned short*)(p + off); off += alignup((size_t)BATCH * HID * 2);
    unsigned short* Zb = (unsigned short*)(p + off); off += alignup((size_t)BATCH * LAT * 2);
    unsigned short* H2 = (unsigned short*)(p + off); off += alignup((size_t)BATCH * HID * 2);
    (void)ws_size; (void)in_sizes; (void)n_in; (void)out_size;

    setup_kernel<<<1, 256, 0, stream>>>(label, meta, out);
    gather_kernel<<<BATCH, 256, 0, stream>>>(img, meta, Xg);

    // L1: Xg @ enc_w1 -> P1, split-K=4 (NT=12, 1344 blocks)
    gemm_kernel<DIM, 4, HID, false><<<dim3(HID / 64, GRID_TILES, 4), 256, 0, stream>>>(
        Xg, enc_w1, nullptr, P1, nullptr, nullptr, meta);
    reduce_kernel<HID, 4, true><<<BATCH * HID / 2048, 256, 0, stream>>>(P1, enc_b1, meta, H1);

    // L2: H1 @ enc_w2 -> P2, split-K=4 (NT=2, 672 blocks)
    gemm_kernel<HID, 4, LAT, false><<<dim3(LAT / 64, GRID_TILES, 4), 256, 0, stream>>>(
        H1, enc_w2, nullptr, P2, nullptr, nullptr, meta);
    reduce_kernel<LAT, 4, false><<<BATCH * LAT / 2048, 256, 0, stream>>>(P2, enc_b2, meta, Zb);

    // L3: Zb @ dec_w1 -> P3, split-K=2 (NT=2, 672 blocks)
    gemm_kernel<LAT, 2, HID, false><<<dim3(HID / 64, GRID_TILES, 2), 256, 0, stream>>>(
        Zb, dec_w1, nullptr, P3, nullptr, nullptr, meta);
    reduce_kernel<HID, 2, true><<<BATCH * HID / 2048, 256, 0, stream>>>(P3, dec_b1, meta, H2);

    // L4: H2 @ dec_w2 + b4 -> scatter + loss (NT=8, 2016 blocks)
    gemm_kernel<HID, 1, DIM, true><<<dim3(DIM / 64, GRID_TILES, 1), 256, 0, stream>>>(
        H2, dec_w2, dec_b2, nullptr, out, img, meta);
}